// Round 2
// baseline (300.212 us; speedup 1.0000x reference)
//
#include <hip/hip_runtime.h>
#include <stdint.h>

typedef __attribute__((ext_vector_type(8))) __bf16 bf16x8;
typedef __attribute__((ext_vector_type(4))) float f32x4;
typedef __attribute__((ext_vector_type(8))) unsigned short u16x8;

__device__ __forceinline__ unsigned short f2bf(float f) {
  union { float f; unsigned u; } v; v.f = f;
  return (unsigned short)((v.u + 0x7FFFu + ((v.u >> 16) & 1u)) >> 16);
}

__device__ __forceinline__ void gload16(const void* g, void* l) {
  __builtin_amdgcn_global_load_lds(
      (const __attribute__((address_space(1))) void*)g,
      (__attribute__((address_space(3))) void*)l, 16, 0, 0);
}

// ---------------------------------------------------------------------------
// pack x: fp32 (8,4096,768) -> bf16 [32768][768] with window permutation
// ---------------------------------------------------------------------------
__global__ __launch_bounds__(256) void pack_x_kernel(const float* __restrict__ x,
                                                     unsigned short* __restrict__ xw) {
  int idx = blockIdx.x * 256 + threadIdx.x;   // < 32768*96
  int m = idx / 96;
  int p = idx - m * 96;
  int win = m >> 6, tok = m & 63;
  int b = win >> 6, wh = (win >> 3) & 7, ww = win & 7;
  int r = tok >> 3, c = tok & 7;
  size_t xoff = ((size_t)b * 4096 + (wh * 8 + r) * 64 + (ww * 8 + c)) * 768 + p * 8;
  const float* src = x + xoff;
  u16x8 o;
#pragma unroll
  for (int j = 0; j < 8; ++j) o[j] = f2bf(src[j]);
  *(u16x8*)(xw + (size_t)m * 768 + p * 8) = o;
}

__global__ __launch_bounds__(256) void pack_w_kernel(const float* __restrict__ qkvw,
                                                     const float* __restrict__ projw,
                                                     unsigned short* __restrict__ wq,
                                                     unsigned short* __restrict__ wp) {
  int idx = blockIdx.x * 256 + threadIdx.x;   // < 294912
  const float* src;
  unsigned short* dst;
  if (idx < 221184) { src = qkvw + (size_t)idx * 8; dst = wq + (size_t)idx * 8; }
  else { int i2 = idx - 221184; src = projw + (size_t)i2 * 8; dst = wp + (size_t)i2 * 8; }
  u16x8 o;
#pragma unroll
  for (int j = 0; j < 8; ++j) o[j] = f2bf(src[j]);
  *(u16x8*)dst = o;
}

// ---------------------------------------------------------------------------
// 256x256-tile GEMM, BK=32, 4-deep LDS ring, counted-vmcnt pipeline.
// C[M][N] = A[M][768] * B[N][768]^T (+bias). 8 waves (2M x 4N), 512 thr.
// LDS: 4 slots x (A 256x32 | B 256x32) bf16 = 4 x 32KB = 128KB (dynamic).
// Swizzle: 16B granule g_phys = g_log ^ (row & 3)  (both stage-src and read).
// Schedule per K-tile t (slot t&3), staging tile t+2 (slot (t+2)&3):
//   P0: ds_read A(m0-3)+B(n0-3) | stage A(t+2) | bar | 16 MFMA | bar
//   P1: ds_read A(m4-7)         | stage B(t+2) | vmcnt(4) | bar | 16 MFMA | bar
// vmcnt(4): tile t+1's 4 loads landed, tile t+2's 4 still in flight.
// ---------------------------------------------------------------------------
template <int N, bool PROJ>
__global__ __launch_bounds__(512) void gemm256_kernel(
    const unsigned short* __restrict__ A, const unsigned short* __restrict__ Bm,
    const float* __restrict__ bias, void* __restrict__ Cout) {
  constexpr int K = 768;
  constexpr int NT = K / 32;     // 24 K-tiles
  constexpr int NBN = N / 256;
  extern __shared__ char smem[];

  const int tid = threadIdx.x;
  const int wave = tid >> 6;
  const int lane = tid & 63;
  const int wm = wave >> 2;      // 0..1 (M half)
  const int wn = wave & 3;       // 0..3 (N quarter)

  // XCD-aware swizzle (gridDim % 8 == 0), N-fastest within chunk
  const int cpx = gridDim.x >> 3;
  const int bid = (blockIdx.x & 7) * cpx + (blockIdx.x >> 3);
  const int tm = (bid / NBN) * 256;
  const int tn = (bid % NBN) * 256;

  // ---- staging addresses: chunk c = j*512 + tid, j in {0,1}; row=c>>2,
  // phys granule = c&3, logical granule = (c&3)^((c>>2)&3) ----
  const int c0 = tid, c1 = 512 + tid;
  const int r0 = c0 >> 2, r1 = c1 >> 2;
  const int g0 = ((c0 & 3) ^ (r0 & 3)) * 8;
  const int g1 = ((c1 & 3) ^ (r1 & 3)) * 8;
  const unsigned short* gA0 = A + (size_t)(tm + r0) * K + g0;
  const unsigned short* gA1 = A + (size_t)(tm + r1) * K + g1;
  const unsigned short* gB0 = Bm + (size_t)(tn + r0) * K + g0;
  const unsigned short* gB1 = Bm + (size_t)(tn + r1) * K + g1;
  // wave-uniform LDS dest bases (HW adds lane*16)
  const int ldsA0 = wave * 1024;
  const int ldsA1 = 8192 + wave * 1024;
  const int ldsB0 = 16384 + wave * 1024;
  const int ldsB1 = 16384 + 8192 + wave * 1024;

  // ---- prologue: stage tiles 0 and 1 ----
  {
    char* s0 = smem;
    char* s1 = smem + 32768;
    gload16(gA0, s0 + ldsA0); gload16(gA1, s0 + ldsA1);
    gload16(gB0, s0 + ldsB0); gload16(gB1, s0 + ldsB1);
    gload16(gA0 + 32, s1 + ldsA0); gload16(gA1 + 32, s1 + ldsA1);
    gload16(gB0 + 32, s1 + ldsB0); gload16(gB1 + 32, s1 + ldsB1);
  }
  asm volatile("s_waitcnt vmcnt(4)" ::: "memory");
  asm volatile("s_barrier" ::: "memory");

  const int lrow = lane & 15;
  const int lg8 = ((lane >> 4) ^ (lane & 3)) * 8;  // swizzled granule (elems)

  f32x4 acc[8][4] = {};

  for (int t = 0; t < NT; ++t) {
    const unsigned short* sAt = (const unsigned short*)(smem + ((t & 3) << 15));
    const unsigned short* sBt = sAt + 8192;

    // ================= phase 0 =================
    bf16x8 a[4], b[4];
#pragma unroll
    for (int mi = 0; mi < 4; ++mi)
      a[mi] = *(const bf16x8*)(sAt + (wm * 128 + mi * 16 + lrow) * 32 + lg8);
#pragma unroll
    for (int ni = 0; ni < 4; ++ni)
      b[ni] = *(const bf16x8*)(sBt + (wn * 64 + ni * 16 + lrow) * 32 + lg8);
    if (t + 2 < NT) {
      char* sb = smem + (((t + 2) & 3) << 15);
      gload16(gA0 + (t + 2) * 32, sb + ldsA0);
      gload16(gA1 + (t + 2) * 32, sb + ldsA1);
    }
    asm volatile("s_barrier" ::: "memory");
    __builtin_amdgcn_s_setprio(1);
#pragma unroll
    for (int mi = 0; mi < 4; ++mi)
#pragma unroll
      for (int ni = 0; ni < 4; ++ni)
        acc[mi][ni] = __builtin_amdgcn_mfma_f32_16x16x32_bf16(a[mi], b[ni], acc[mi][ni], 0, 0, 0);
    __builtin_amdgcn_s_setprio(0);
    asm volatile("s_barrier" ::: "memory");

    // ================= phase 1 =================
#pragma unroll
    for (int mi = 0; mi < 4; ++mi)
      a[mi] = *(const bf16x8*)(sAt + (wm * 128 + 64 + mi * 16 + lrow) * 32 + lg8);
    if (t + 2 < NT) {
      char* sb = smem + (((t + 2) & 3) << 15);
      gload16(gB0 + (t + 2) * 32, sb + ldsB0);
      gload16(gB1 + (t + 2) * 32, sb + ldsB1);
    }
    if (t < NT - 2)
      asm volatile("s_waitcnt vmcnt(4)" ::: "memory");
    else if (t == NT - 2)
      asm volatile("s_waitcnt vmcnt(0)" ::: "memory");
    asm volatile("s_barrier" ::: "memory");
    __builtin_amdgcn_s_setprio(1);
#pragma unroll
    for (int mi = 0; mi < 4; ++mi)
#pragma unroll
      for (int ni = 0; ni < 4; ++ni)
        acc[4 + mi][ni] = __builtin_amdgcn_mfma_f32_16x16x32_bf16(a[mi], b[ni], acc[4 + mi][ni], 0, 0, 0);
    __builtin_amdgcn_s_setprio(0);
    asm volatile("s_barrier" ::: "memory");
  }

  // ---- epilogue ----
  const int crow = tm + wm * 128 + ((lane >> 4) << 2);
  const int ccol0 = tn + wn * 64 + lrow;
  if constexpr (!PROJ) {
    unsigned short* C = (unsigned short*)Cout;
#pragma unroll
    for (int ni = 0; ni < 4; ++ni) {
      const int col = ccol0 + ni * 16;
      const float bv = bias[col];
#pragma unroll
      for (int mi = 0; mi < 8; ++mi)
#pragma unroll
        for (int r = 0; r < 4; ++r)
          C[(size_t)(crow + mi * 16 + r) * N + col] = f2bf(acc[mi][ni][r] + bv);
    }
  } else {
    float* out = (float*)Cout;
#pragma unroll
    for (int mi = 0; mi < 8; ++mi)
#pragma unroll
      for (int r = 0; r < 4; ++r) {
        int m = crow + mi * 16 + r;
        int win = m >> 6, tok = m & 63;
        int bb = win >> 6, wh = (win >> 3) & 7, ww = win & 7;
        int rr = tok >> 3, cc = tok & 7;
        float* op = out + ((size_t)bb * 4096 + (wh * 8 + rr) * 64 + (ww * 8 + cc)) * 768;
#pragma unroll
        for (int ni = 0; ni < 4; ++ni) {
          int col = ccol0 + ni * 16;
          op[col] = acc[mi][ni][r] + bias[col];
        }
      }
  }
}

// ---------------------------------------------------------------------------
// Attention: one wave per (window, head), unchanged from R1 (passing, ~20us)
// ---------------------------------------------------------------------------
__global__ __launch_bounds__(64) void attn_kernel(const unsigned short* __restrict__ qkv,
                                                  unsigned short* __restrict__ attnout) {
  __shared__ unsigned short sQ[64 * 64];
  __shared__ unsigned short sK[64 * 64];
  __shared__ unsigned short sVT[64 * 64];
  const int lane = threadIdx.x;
  const int win = blockIdx.x / 12;
  const int head = blockIdx.x - win * 12;
  const size_t row0 = (size_t)win * 64;
  const int qoff = head * 64, koff = 768 + head * 64, voff = 1536 + head * 64;

#pragma unroll
  for (int i = 0; i < 8; ++i) {
    int e = lane + i * 64;
    int row = e >> 3, cb = (e & 7) * 8;
    gload16(qkv + (row0 + row) * 2304 + qoff + cb, (char*)sQ + i * 1024);
    gload16(qkv + (row0 + row) * 2304 + koff + cb, (char*)sK + i * 1024);
  }
  {
    const unsigned short* gv = qkv + (row0 + lane) * 2304 + voff;
#pragma unroll
    for (int j = 0; j < 8; ++j) {
      u16x8 v = *(const u16x8*)(gv + j * 8);
#pragma unroll
      for (int d = 0; d < 8; ++d) sVT[(j * 8 + d) * 64 + lane] = v[d];
    }
  }
  __syncthreads();

  const int lrow = lane & 15;
  const int lkb = (lane >> 4) * 8;

  f32x4 s[4][4] = {};
#pragma unroll
  for (int ks = 0; ks < 2; ++ks) {
    bf16x8 qf[4], kf[4];
#pragma unroll
    for (int mi = 0; mi < 4; ++mi) qf[mi] = *(const bf16x8*)&sQ[(mi * 16 + lrow) * 64 + ks * 32 + lkb];
#pragma unroll
    for (int ni = 0; ni < 4; ++ni) kf[ni] = *(const bf16x8*)&sK[(ni * 16 + lrow) * 64 + ks * 32 + lkb];
#pragma unroll
    for (int mi = 0; mi < 4; ++mi)
#pragma unroll
      for (int ni = 0; ni < 4; ++ni)
        s[mi][ni] = __builtin_amdgcn_mfma_f32_16x16x32_bf16(qf[mi], kf[ni], s[mi][ni], 0, 0, 0);
  }

  float p[4][4][4];
#pragma unroll
  for (int mi = 0; mi < 4; ++mi) {
#pragma unroll
    for (int r = 0; r < 4; ++r) {
      float v0 = s[mi][0][r] * 0.125f, v1 = s[mi][1][r] * 0.125f;
      float v2 = s[mi][2][r] * 0.125f, v3 = s[mi][3][r] * 0.125f;
      float mx = fmaxf(fmaxf(v0, v1), fmaxf(v2, v3));
      mx = fmaxf(mx, __shfl_xor(mx, 1));
      mx = fmaxf(mx, __shfl_xor(mx, 2));
      mx = fmaxf(mx, __shfl_xor(mx, 4));
      mx = fmaxf(mx, __shfl_xor(mx, 8));
      float e0 = __expf(v0 - mx), e1 = __expf(v1 - mx);
      float e2 = __expf(v2 - mx), e3 = __expf(v3 - mx);
      float sm = e0 + e1 + e2 + e3;
      sm += __shfl_xor(sm, 1);
      sm += __shfl_xor(sm, 2);
      sm += __shfl_xor(sm, 4);
      sm += __shfl_xor(sm, 8);
      float inv = 1.0f / sm;
      p[mi][0][r] = e0 * inv; p[mi][1][r] = e1 * inv;
      p[mi][2][r] = e2 * inv; p[mi][3][r] = e3 * inv;
    }
  }

  __syncthreads();
#pragma unroll
  for (int mi = 0; mi < 4; ++mi)
#pragma unroll
    for (int ni = 0; ni < 4; ++ni)
#pragma unroll
      for (int r = 0; r < 4; ++r)
        sK[(mi * 16 + (lane >> 4) * 4 + r) * 64 + ni * 16 + lrow] = f2bf(p[mi][ni][r]);
  __syncthreads();

  f32x4 o[4][4] = {};
#pragma unroll
  for (int ks = 0; ks < 2; ++ks) {
    bf16x8 pf[4], vf[4];
#pragma unroll
    for (int mi = 0; mi < 4; ++mi) pf[mi] = *(const bf16x8*)&sK[(mi * 16 + lrow) * 64 + ks * 32 + lkb];
#pragma unroll
    for (int ni = 0; ni < 4; ++ni) vf[ni] = *(const bf16x8*)&sVT[(ni * 16 + lrow) * 64 + ks * 32 + lkb];
#pragma unroll
    for (int mi = 0; mi < 4; ++mi)
#pragma unroll
      for (int ni = 0; ni < 4; ++ni)
        o[mi][ni] = __builtin_amdgcn_mfma_f32_16x16x32_bf16(pf[mi], vf[ni], o[mi][ni], 0, 0, 0);
  }

#pragma unroll
  for (int mi = 0; mi < 4; ++mi)
#pragma unroll
    for (int ni = 0; ni < 4; ++ni) {
      int col = head * 64 + ni * 16 + lrow;
#pragma unroll
      for (int r = 0; r < 4; ++r) {
        int trow = mi * 16 + (lane >> 4) * 4 + r;
        attnout[(row0 + trow) * 768 + col] = f2bf(o[mi][ni][r]);
      }
    }
}

extern "C" void kernel_launch(void* const* d_in, const int* in_sizes, int n_in,
                              void* d_out, int out_size, void* d_ws, size_t ws_size,
                              hipStream_t stream) {
  (void)in_sizes; (void)n_in; (void)out_size; (void)ws_size;
  const float* x = (const float*)d_in[0];
  const float* qkv_w = (const float*)d_in[1];
  const float* qkv_b = (const float*)d_in[2];
  const float* proj_w = (const float*)d_in[3];
  const float* proj_b = (const float*)d_in[4];
  float* out = (float*)d_out;

  char* ws = (char*)d_ws;
  unsigned short* xw   = (unsigned short*)(ws);                          // 50.3MB, reused as attnout
  unsigned short* qkvB = (unsigned short*)(ws + 50331648);               // 151MB
  unsigned short* wq   = (unsigned short*)(ws + 50331648 + 150994944);
  unsigned short* wp   = (unsigned short*)(ws + 50331648 + 150994944 + 3538944);

  // allow 128KB dynamic LDS (idempotent; ignore error if unsupported)
  (void)hipFuncSetAttribute((const void*)(gemm256_kernel<2304, false>),
                            hipFuncAttributeMaxDynamicSharedMemorySize, 131072);
  (void)hipFuncSetAttribute((const void*)(gemm256_kernel<768, true>),
                            hipFuncAttributeMaxDynamicSharedMemorySize, 131072);

  pack_x_kernel<<<12288, 256, 0, stream>>>(x, xw);
  pack_w_kernel<<<1152, 256, 0, stream>>>(qkv_w, proj_w, wq, wp);
  gemm256_kernel<2304, false><<<1152, 512, 131072, stream>>>(xw, wq, qkv_b, qkvB);
  attn_kernel<<<6144, 64, 0, stream>>>(qkvB, xw);
  gemm256_kernel<768, true><<<384, 512, 131072, stream>>>(xw, wp, proj_b, out);
}

// Round 3
// 282.553 us; speedup vs baseline: 1.0625x; 1.0625x over previous
//
#include <hip/hip_runtime.h>
#include <stdint.h>

typedef __attribute__((ext_vector_type(8))) __bf16 bf16x8;
typedef __attribute__((ext_vector_type(4))) float f32x4;
typedef __attribute__((ext_vector_type(8))) unsigned short u16x8;

__device__ __forceinline__ unsigned short f2bf(float f) {
  union { float f; unsigned u; } v; v.f = f;
  return (unsigned short)((v.u + 0x7FFFu + ((v.u >> 16) & 1u)) >> 16);
}

__device__ __forceinline__ void gload16(const void* g, void* l) {
  __builtin_amdgcn_global_load_lds(
      (const __attribute__((address_space(1))) void*)g,
      (__attribute__((address_space(3))) void*)l, 16, 0, 0);
}

// ---------------------------------------------------------------------------
// pack x: fp32 (8,4096,768) -> bf16 [32768][768] with window permutation
// ---------------------------------------------------------------------------
__global__ __launch_bounds__(256) void pack_x_kernel(const float* __restrict__ x,
                                                     unsigned short* __restrict__ xw) {
  int idx = blockIdx.x * 256 + threadIdx.x;   // < 32768*96
  int m = idx / 96;
  int p = idx - m * 96;
  int win = m >> 6, tok = m & 63;
  int b = win >> 6, wh = (win >> 3) & 7, ww = win & 7;
  int r = tok >> 3, c = tok & 7;
  size_t xoff = ((size_t)b * 4096 + (wh * 8 + r) * 64 + (ww * 8 + c)) * 768 + p * 8;
  const float* src = x + xoff;
  u16x8 o;
#pragma unroll
  for (int j = 0; j < 8; ++j) o[j] = f2bf(src[j]);
  *(u16x8*)(xw + (size_t)m * 768 + p * 8) = o;
}

__global__ __launch_bounds__(256) void pack_w_kernel(const float* __restrict__ qkvw,
                                                     const float* __restrict__ projw,
                                                     unsigned short* __restrict__ wq,
                                                     unsigned short* __restrict__ wp) {
  int idx = blockIdx.x * 256 + threadIdx.x;   // < 294912
  const float* src;
  unsigned short* dst;
  if (idx < 221184) { src = qkvw + (size_t)idx * 8; dst = wq + (size_t)idx * 8; }
  else { int i2 = idx - 221184; src = projw + (size_t)i2 * 8; dst = wp + (size_t)i2 * 8; }
  u16x8 o;
#pragma unroll
  for (int j = 0; j < 8; ++j) o[j] = f2bf(src[j]);
  *(u16x8*)dst = o;
}

// ---------------------------------------------------------------------------
// 256x256-tile GEMM, BK=32, 4-deep LDS ring, 1 barrier + counted vmcnt / tile.
// C[M][N] = A[M][768] * B[N][768]^T (+bias). 8 waves (2M x 4N), 512 thr.
// LDS: 4 slots x (A 256x32 | B 256x32) bf16 = 128KB (dynamic), 1 block/CU.
// Swizzle: 16B granule phys = logical ^ ((row>>1)&3)  [decorrelated from the
// row&1 bank bit -> 16 lanes span 8 bank-quads, 2-way = free].
// Per tile t: stage(t+2) | 12 ds_read (both k-halves) | vmcnt(4) | s_barrier |
// 32 MFMA. Ring-4 + 1 bar/tile proven WAR/RAW-safe (see analysis).
// ---------------------------------------------------------------------------
template <int N, bool PROJ>
__global__ __launch_bounds__(512) void gemm256_kernel(
    const unsigned short* __restrict__ A, const unsigned short* __restrict__ Bm,
    const float* __restrict__ bias, void* __restrict__ Cout) {
  constexpr int K = 768;
  constexpr int NT = K / 32;     // 24 K-tiles
  constexpr int NBN = N / 256;
  extern __shared__ char smem[];

  const int tid = threadIdx.x;
  const int wave = tid >> 6;
  const int lane = tid & 63;
  const int wm = wave >> 2;      // 0..1 (M half)
  const int wn = wave & 3;       // 0..3 (N quarter)

  // XCD-aware swizzle (gridDim % 8 == 0), N-fastest within chunk
  const int cpx = gridDim.x >> 3;
  const int bid = (blockIdx.x & 7) * cpx + (blockIdx.x >> 3);
  const int tm = (bid / NBN) * 256;
  const int tn = (bid % NBN) * 256;

  // staging: chunk c = j*512 + tid; row = c>>2, phys granule = c&3,
  // logical granule = (c&3) ^ ((c>>3)&3)   [swz(row) = (row>>1)&3]
  const int c0 = tid, c1 = 512 + tid;
  const int r0 = c0 >> 2, r1 = c1 >> 2;
  const int g0 = ((c0 & 3) ^ ((c0 >> 3) & 3)) * 8;
  const int g1 = ((c1 & 3) ^ ((c1 >> 3) & 3)) * 8;
  const unsigned short* gA0 = A + (size_t)(tm + r0) * K + g0;
  const unsigned short* gA1 = A + (size_t)(tm + r1) * K + g1;
  const unsigned short* gB0 = Bm + (size_t)(tn + r0) * K + g0;
  const unsigned short* gB1 = Bm + (size_t)(tn + r1) * K + g1;
  // wave-uniform LDS dest bases (HW adds lane*16)
  const int ldsA0 = wave * 1024;
  const int ldsA1 = 8192 + wave * 1024;
  const int ldsB0 = 16384 + wave * 1024;
  const int ldsB1 = 24576 + wave * 1024;

  // ---- prologue: stage tiles 0 and 1; ensure tile 0 resident ----
  {
    char* s0 = smem;
    char* s1 = smem + 32768;
    gload16(gA0, s0 + ldsA0); gload16(gA1, s0 + ldsA1);
    gload16(gB0, s0 + ldsB0); gload16(gB1, s0 + ldsB1);
    gload16(gA0 + 32, s1 + ldsA0); gload16(gA1 + 32, s1 + ldsA1);
    gload16(gB0 + 32, s1 + ldsB0); gload16(gB1 + 32, s1 + ldsB1);
  }
  asm volatile("s_waitcnt vmcnt(4)" ::: "memory");
  asm volatile("s_barrier" ::: "memory");

  const int lrow = lane & 15;
  // read granule: logical q = lane>>4, phys = q ^ ((row>>1)&3); row&15 == lrow
  const int lg8 = ((lane >> 4) ^ ((lane >> 1) & 3)) * 8;

  f32x4 acc[8][4] = {};

  for (int t = 0; t < NT; ++t) {
    const unsigned short* sAt = (const unsigned short*)(smem + ((t & 3) << 15));
    const unsigned short* sBt = sAt + 8192;

    // stage tile t+2 (slot (t+2)&3) — issue first, longest latency
    if (t + 2 < NT) {
      char* sb = smem + (((t + 2) & 3) << 15);
      gload16(gA0 + (t + 2) * 32, sb + ldsA0);
      gload16(gA1 + (t + 2) * 32, sb + ldsA1);
      gload16(gB0 + (t + 2) * 32, sb + ldsB0);
      gload16(gB1 + (t + 2) * 32, sb + ldsB1);
    }

    // all 12 fragment reads for this tile
    bf16x8 a0[4], b0[4], a1[4];
#pragma unroll
    for (int mi = 0; mi < 4; ++mi)
      a0[mi] = *(const bf16x8*)(sAt + (wm * 128 + mi * 16 + lrow) * 32 + lg8);
#pragma unroll
    for (int ni = 0; ni < 4; ++ni)
      b0[ni] = *(const bf16x8*)(sBt + (wn * 64 + ni * 16 + lrow) * 32 + lg8);
#pragma unroll
    for (int mi = 0; mi < 4; ++mi)
      a1[mi] = *(const bf16x8*)(sAt + (wm * 128 + 64 + mi * 16 + lrow) * 32 + lg8);

    // counted wait: after stage issue, in-flight = t+1(4) + t+2(4);
    // vmcnt(4) -> tile t+1 resident across all waves at the barrier
    if (t < NT - 2)
      asm volatile("s_waitcnt vmcnt(4)" ::: "memory");
    else if (t == NT - 2)
      asm volatile("s_waitcnt vmcnt(0)" ::: "memory");
    asm volatile("s_barrier" ::: "memory");

    __builtin_amdgcn_s_setprio(1);
#pragma unroll
    for (int mi = 0; mi < 4; ++mi)
#pragma unroll
      for (int ni = 0; ni < 4; ++ni)
        acc[mi][ni] = __builtin_amdgcn_mfma_f32_16x16x32_bf16(a0[mi], b0[ni], acc[mi][ni], 0, 0, 0);
#pragma unroll
    for (int mi = 0; mi < 4; ++mi)
#pragma unroll
      for (int ni = 0; ni < 4; ++ni)
        acc[4 + mi][ni] = __builtin_amdgcn_mfma_f32_16x16x32_bf16(a1[mi], b0[ni], acc[4 + mi][ni], 0, 0, 0);
    __builtin_amdgcn_s_setprio(0);
  }

  // ---- epilogue ----
  const int crow = tm + wm * 128 + ((lane >> 4) << 2);
  const int ccol0 = tn + wn * 64 + lrow;
  if constexpr (!PROJ) {
    unsigned short* C = (unsigned short*)Cout;
#pragma unroll
    for (int ni = 0; ni < 4; ++ni) {
      const int col = ccol0 + ni * 16;
      const float bv = bias[col];
#pragma unroll
      for (int mi = 0; mi < 8; ++mi)
#pragma unroll
        for (int r = 0; r < 4; ++r)
          C[(size_t)(crow + mi * 16 + r) * N + col] = f2bf(acc[mi][ni][r] + bv);
    }
  } else {
    float* out = (float*)Cout;
#pragma unroll
    for (int mi = 0; mi < 8; ++mi)
#pragma unroll
      for (int r = 0; r < 4; ++r) {
        int m = crow + mi * 16 + r;
        int win = m >> 6, tok = m & 63;
        int bb = win >> 6, wh = (win >> 3) & 7, ww = win & 7;
        int rr = tok >> 3, cc = tok & 7;
        float* op = out + ((size_t)bb * 4096 + (wh * 8 + rr) * 64 + (ww * 8 + cc)) * 768;
#pragma unroll
        for (int ni = 0; ni < 4; ++ni) {
          int col = ccol0 + ni * 16;
          op[col] = acc[mi][ni][r] + bias[col];
        }
      }
  }
}

// ---------------------------------------------------------------------------
// Attention: one wave per (window, head) — unchanged (passing, ~20us)
// ---------------------------------------------------------------------------
__global__ __launch_bounds__(64) void attn_kernel(const unsigned short* __restrict__ qkv,
                                                  unsigned short* __restrict__ attnout) {
  __shared__ unsigned short sQ[64 * 64];
  __shared__ unsigned short sK[64 * 64];
  __shared__ unsigned short sVT[64 * 64];
  const int lane = threadIdx.x;
  const int win = blockIdx.x / 12;
  const int head = blockIdx.x - win * 12;
  const size_t row0 = (size_t)win * 64;
  const int qoff = head * 64, koff = 768 + head * 64, voff = 1536 + head * 64;

#pragma unroll
  for (int i = 0; i < 8; ++i) {
    int e = lane + i * 64;
    int row = e >> 3, cb = (e & 7) * 8;
    gload16(qkv + (row0 + row) * 2304 + qoff + cb, (char*)sQ + i * 1024);
    gload16(qkv + (row0 + row) * 2304 + koff + cb, (char*)sK + i * 1024);
  }
  {
    const unsigned short* gv = qkv + (row0 + lane) * 2304 + voff;
#pragma unroll
    for (int j = 0; j < 8; ++j) {
      u16x8 v = *(const u16x8*)(gv + j * 8);
#pragma unroll
      for (int d = 0; d < 8; ++d) sVT[(j * 8 + d) * 64 + lane] = v[d];
    }
  }
  __syncthreads();

  const int lrow = lane & 15;
  const int lkb = (lane >> 4) * 8;

  f32x4 s[4][4] = {};
#pragma unroll
  for (int ks = 0; ks < 2; ++ks) {
    bf16x8 qf[4], kf[4];
#pragma unroll
    for (int mi = 0; mi < 4; ++mi) qf[mi] = *(const bf16x8*)&sQ[(mi * 16 + lrow) * 64 + ks * 32 + lkb];
#pragma unroll
    for (int ni = 0; ni < 4; ++ni) kf[ni] = *(const bf16x8*)&sK[(ni * 16 + lrow) * 64 + ks * 32 + lkb];
#pragma unroll
    for (int mi = 0; mi < 4; ++mi)
#pragma unroll
      for (int ni = 0; ni < 4; ++ni)
        s[mi][ni] = __builtin_amdgcn_mfma_f32_16x16x32_bf16(qf[mi], kf[ni], s[mi][ni], 0, 0, 0);
  }

  float p[4][4][4];
#pragma unroll
  for (int mi = 0; mi < 4; ++mi) {
#pragma unroll
    for (int r = 0; r < 4; ++r) {
      float v0 = s[mi][0][r] * 0.125f, v1 = s[mi][1][r] * 0.125f;
      float v2 = s[mi][2][r] * 0.125f, v3 = s[mi][3][r] * 0.125f;
      float mx = fmaxf(fmaxf(v0, v1), fmaxf(v2, v3));
      mx = fmaxf(mx, __shfl_xor(mx, 1));
      mx = fmaxf(mx, __shfl_xor(mx, 2));
      mx = fmaxf(mx, __shfl_xor(mx, 4));
      mx = fmaxf(mx, __shfl_xor(mx, 8));
      float e0 = __expf(v0 - mx), e1 = __expf(v1 - mx);
      float e2 = __expf(v2 - mx), e3 = __expf(v3 - mx);
      float sm = e0 + e1 + e2 + e3;
      sm += __shfl_xor(sm, 1);
      sm += __shfl_xor(sm, 2);
      sm += __shfl_xor(sm, 4);
      sm += __shfl_xor(sm, 8);
      float inv = 1.0f / sm;
      p[mi][0][r] = e0 * inv; p[mi][1][r] = e1 * inv;
      p[mi][2][r] = e2 * inv; p[mi][3][r] = e3 * inv;
    }
  }

  __syncthreads();
#pragma unroll
  for (int mi = 0; mi < 4; ++mi)
#pragma unroll
    for (int ni = 0; ni < 4; ++ni)
#pragma unroll
      for (int r = 0; r < 4; ++r)
        sK[(mi * 16 + (lane >> 4) * 4 + r) * 64 + ni * 16 + lrow] = f2bf(p[mi][ni][r]);
  __syncthreads();

  f32x4 o[4][4] = {};
#pragma unroll
  for (int ks = 0; ks < 2; ++ks) {
    bf16x8 pf[4], vf[4];
#pragma unroll
    for (int mi = 0; mi < 4; ++mi) pf[mi] = *(const bf16x8*)&sK[(mi * 16 + lrow) * 64 + ks * 32 + lkb];
#pragma unroll
    for (int ni = 0; ni < 4; ++ni) vf[ni] = *(const bf16x8*)&sVT[(ni * 16 + lrow) * 64 + ks * 32 + lkb];
#pragma unroll
    for (int mi = 0; mi < 4; ++mi)
#pragma unroll
      for (int ni = 0; ni < 4; ++ni)
        o[mi][ni] = __builtin_amdgcn_mfma_f32_16x16x32_bf16(pf[mi], vf[ni], o[mi][ni], 0, 0, 0);
  }

#pragma unroll
  for (int mi = 0; mi < 4; ++mi)
#pragma unroll
    for (int ni = 0; ni < 4; ++ni) {
      int col = head * 64 + ni * 16 + lrow;
#pragma unroll
      for (int r = 0; r < 4; ++r) {
        int trow = mi * 16 + (lane >> 4) * 4 + r;
        attnout[(row0 + trow) * 768 + col] = f2bf(o[mi][ni][r]);
      }
    }
}

extern "C" void kernel_launch(void* const* d_in, const int* in_sizes, int n_in,
                              void* d_out, int out_size, void* d_ws, size_t ws_size,
                              hipStream_t stream) {
  (void)in_sizes; (void)n_in; (void)out_size; (void)ws_size;
  const float* x = (const float*)d_in[0];
  const float* qkv_w = (const float*)d_in[1];
  const float* qkv_b = (const float*)d_in[2];
  const float* proj_w = (const float*)d_in[3];
  const float* proj_b = (const float*)d_in[4];
  float* out = (float*)d_out;

  char* ws = (char*)d_ws;
  unsigned short* xw   = (unsigned short*)(ws);                          // 50.3MB, reused as attnout
  unsigned short* qkvB = (unsigned short*)(ws + 50331648);               // 151MB
  unsigned short* wq   = (unsigned short*)(ws + 50331648 + 150994944);
  unsigned short* wp   = (unsigned short*)(ws + 50331648 + 150994944 + 3538944);

  (void)hipFuncSetAttribute((const void*)(gemm256_kernel<2304, false>),
                            hipFuncAttributeMaxDynamicSharedMemorySize, 131072);
  (void)hipFuncSetAttribute((const void*)(gemm256_kernel<768, true>),
                            hipFuncAttributeMaxDynamicSharedMemorySize, 131072);

  pack_x_kernel<<<12288, 256, 0, stream>>>(x, xw);
  pack_w_kernel<<<1152, 256, 0, stream>>>(qkv_w, proj_w, wq, wp);
  gemm256_kernel<2304, false><<<1152, 512, 131072, stream>>>(xw, wq, qkv_b, qkvB);
  attn_kernel<<<6144, 64, 0, stream>>>(qkvB, xw);
  gemm256_kernel<768, true><<<384, 512, 131072, stream>>>(xw, wp, proj_b, out);
}